// Round 1
// baseline (1133.412 us; speedup 1.0000x reference)
//
#include <hip/hip_runtime.h>

#define NEG_INF (-3.402823466e38f)

// ---------------------------------------------------------------------------
// Geometry: B=4, C=96, H=W=256, GS=8 -> gh=gw=32, N=4096 windows, P=64 tokens
// dsxT: [96][4096]   (channel-major window descriptors)
// ---------------------------------------------------------------------------

__device__ __forceinline__ void ins3(float (&tv)[3], int (&ti)[3], float v, int ci)
{
    if (v > tv[0] || (v == tv[0] && ci < ti[0])) {
        tv[2] = tv[1]; ti[2] = ti[1];
        tv[1] = tv[0]; ti[1] = ti[0];
        tv[0] = v;     ti[0] = ci;
    } else if (v > tv[1] || (v == tv[1] && ci < ti[1])) {
        tv[2] = tv[1]; ti[2] = ti[1];
        tv[1] = v;     ti[1] = ci;
    } else if (v > tv[2] || (v == tv[2] && ci < ti[2])) {
        tv[2] = v;     ti[2] = ci;
    }
}

// ------------------------- Kernel 1: maxpool --------------------------------
__global__ __launch_bounds__(256) void k_pool(const float* __restrict__ x,
                                              float* __restrict__ dsxT)
{
    int gid = blockIdx.x * 256 + threadIdx.x;   // [0, 96*4096)
    int c = gid >> 12;
    int n = gid & 4095;
    int b = n >> 10, i = (n >> 5) & 31, j = n & 31;
    const float* p = x + (((size_t)(b * 96 + c)) << 16) + i * 2048 + j * 8;
    float4 m0 = *(const float4*)p;
    float4 m1 = *(const float4*)(p + 4);
    #pragma unroll
    for (int r = 1; r < 8; ++r) {
        float4 a0 = *(const float4*)(p + r * 256);
        float4 a1 = *(const float4*)(p + r * 256 + 4);
        m0.x = fmaxf(m0.x, a0.x); m0.y = fmaxf(m0.y, a0.y);
        m0.z = fmaxf(m0.z, a0.z); m0.w = fmaxf(m0.w, a0.w);
        m1.x = fmaxf(m1.x, a1.x); m1.y = fmaxf(m1.y, a1.y);
        m1.z = fmaxf(m1.z, a1.z); m1.w = fmaxf(m1.w, a1.w);
    }
    float m = fmaxf(fmaxf(fmaxf(m0.x, m0.y), fmaxf(m0.z, m0.w)),
                    fmaxf(fmaxf(m1.x, m1.y), fmaxf(m1.z, m1.w)));
    dsxT[c * 4096 + n] = m;
}

// ------------------- Kernel 2: similarity + partial top3 --------------------
// grid 512 = 64 query-tiles x 8 cand-chunks; block 256.
// Each block: 64 queries x 512 candidates, emits per-(query,chunk) top3.
__global__ __launch_bounds__(256) void k_sim(const float* __restrict__ dsxT,
                                             float* __restrict__ pv,
                                             int* __restrict__ pi)
{
    __shared__ __align__(16) float qt[96 * 64];
    __shared__ __align__(16) float ct[96 * 64];

    int t   = threadIdx.x;
    int qti = blockIdx.x >> 3;
    int ch  = blockIdx.x & 7;
    int tyq = t >> 4;     // 0..15 -> 4 queries each
    int txc = t & 15;     // 0..15 -> 4 cands each

    for (int f = t; f < 1536; f += 256) {
        int cr = f >> 4, nf = f & 15;
        *(float4*)&qt[cr * 64 + 4 * nf] =
            *(const float4*)&dsxT[cr * 4096 + qti * 64 + 4 * nf];
    }

    float tv[4][3]; int ti[4][3];
    #pragma unroll
    for (int a = 0; a < 4; ++a)
        #pragma unroll
        for (int k = 0; k < 3; ++k) { tv[a][k] = NEG_INF; ti[a][k] = 0x7fffffff; }

    for (int tile = 0; tile < 8; ++tile) {
        __syncthreads();
        int cbase = ch * 512 + tile * 64;
        for (int f = t; f < 1536; f += 256) {
            int cr = f >> 4, nf = f & 15;
            *(float4*)&ct[cr * 64 + 4 * nf] =
                *(const float4*)&dsxT[cr * 4096 + cbase + 4 * nf];
        }
        __syncthreads();

        float acc[4][4] = {};
        for (int kk = 0; kk < 96; ++kk) {
            float4 qv = *(float4*)&qt[kk * 64 + 4 * tyq];
            float4 cv = *(float4*)&ct[kk * 64 + 4 * txc];
            acc[0][0] = fmaf(qv.x, cv.x, acc[0][0]);
            acc[0][1] = fmaf(qv.x, cv.y, acc[0][1]);
            acc[0][2] = fmaf(qv.x, cv.z, acc[0][2]);
            acc[0][3] = fmaf(qv.x, cv.w, acc[0][3]);
            acc[1][0] = fmaf(qv.y, cv.x, acc[1][0]);
            acc[1][1] = fmaf(qv.y, cv.y, acc[1][1]);
            acc[1][2] = fmaf(qv.y, cv.z, acc[1][2]);
            acc[1][3] = fmaf(qv.y, cv.w, acc[1][3]);
            acc[2][0] = fmaf(qv.z, cv.x, acc[2][0]);
            acc[2][1] = fmaf(qv.z, cv.y, acc[2][1]);
            acc[2][2] = fmaf(qv.z, cv.z, acc[2][2]);
            acc[2][3] = fmaf(qv.z, cv.w, acc[2][3]);
            acc[3][0] = fmaf(qv.w, cv.x, acc[3][0]);
            acc[3][1] = fmaf(qv.w, cv.y, acc[3][1]);
            acc[3][2] = fmaf(qv.w, cv.z, acc[3][2]);
            acc[3][3] = fmaf(qv.w, cv.w, acc[3][3]);
        }
        #pragma unroll
        for (int b2 = 0; b2 < 4; ++b2) {
            int ci = cbase + 4 * txc + b2;
            #pragma unroll
            for (int a = 0; a < 4; ++a) ins3(tv[a], ti[a], acc[a][b2], ci);
        }
    }

    __syncthreads();
    // overlay scratch on ct: sv [64][16][3] floats, si same in ints
    float* svp = ct;
    int*   sip = (int*)&ct[3072];
    #pragma unroll
    for (int a = 0; a < 4; ++a) {
        int q = 4 * tyq + a;
        #pragma unroll
        for (int k = 0; k < 3; ++k) {
            svp[(q * 16 + txc) * 3 + k] = tv[a][k];
            sip[(q * 16 + txc) * 3 + k] = ti[a][k];
        }
    }
    __syncthreads();
    if (t < 64) {
        float bv[3] = {NEG_INF, NEG_INF, NEG_INF};
        int   bi[3] = {0x7fffffff, 0x7fffffff, 0x7fffffff};
        for (int e = 0; e < 48; ++e)
            ins3(bv, bi, svp[t * 48 + e], sip[t * 48 + e]);
        int n = qti * 64 + t;
        #pragma unroll
        for (int k = 0; k < 3; ++k) {
            pv[n * 24 + ch * 3 + k] = bv[k];
            pi[n * 24 + ch * 3 + k] = bi[k];
        }
    }
}

// ---------------- Kernel 2b: final top3 merge + softmax weights -------------
__global__ __launch_bounds__(256) void k_topk(const float* __restrict__ pv,
                                              const int* __restrict__ pi,
                                              float* __restrict__ w3,
                                              int* __restrict__ i3)
{
    int n = blockIdx.x * 256 + threadIdx.x;   // 4096
    float bv[3] = {NEG_INF, NEG_INF, NEG_INF};
    int   bi[3] = {0x7fffffff, 0x7fffffff, 0x7fffffff};
    for (int e = 0; e < 24; ++e)
        ins3(bv, bi, pv[n * 24 + e], pi[n * 24 + e]);
    float e1 = expf(bv[1] - bv[0]);
    float e2 = expf(bv[2] - bv[0]);
    float inv = 1.f / (1.f + e1 + e2);
    w3[n * 3 + 0] = inv;
    w3[n * 3 + 1] = e1 * inv;
    w3[n * 3 + 2] = e2 * inv;
    i3[n * 3 + 0] = bi[0];
    i3[n * 3 + 1] = bi[1];
    i3[n * 3 + 2] = bi[2];
}

// ----------------------- Kernel 3: fused window attention -------------------
__device__ __forceinline__ size_t win_off(int m)
{
    return (((size_t)(m >> 10) * 96) << 16) +
           (size_t)(((m >> 5) & 31) * 2048 + (m & 31) * 8);
}

__device__ __forceinline__ void stage_w(const float* __restrict__ Wg,
                                        float* __restrict__ Wl, int t)
{
    for (int f = t; f < 2304; f += 256) {
        int row = f / 24, q = f % 24;
        *(float4*)&Wl[row * 100 + 4 * q] = *(const float4*)&Wg[row * 96 + 4 * q];
    }
}

// D[64][ds_] = X[64][xs] @ Wl(96x96, stride100) + bias
__device__ __forceinline__ void gemm96(const float* __restrict__ X, int xs,
                                       const float* __restrict__ Wl,
                                       const float* __restrict__ bias,
                                       float* __restrict__ D, int ds_,
                                       int ty, int tx)
{
    float acc[4][6];
    #pragma unroll
    for (int u = 0; u < 6; ++u) {
        float b = bias[6 * tx + u];
        #pragma unroll
        for (int a = 0; a < 4; ++a) acc[a][u] = b;
    }
    for (int c = 0; c < 96; ++c) {
        float xa[4], wu[6];
        #pragma unroll
        for (int a = 0; a < 4; ++a) xa[a] = X[(4 * ty + a) * xs + c];
        #pragma unroll
        for (int u = 0; u < 6; ++u) wu[u] = Wl[c * 100 + 6 * tx + u];
        #pragma unroll
        for (int a = 0; a < 4; ++a)
            #pragma unroll
            for (int u = 0; u < 6; ++u) acc[a][u] = fmaf(xa[a], wu[u], acc[a][u]);
    }
    #pragma unroll
    for (int a = 0; a < 4; ++a)
        #pragma unroll
        for (int u = 0; u < 6; ++u) D[(4 * ty + a) * ds_ + 6 * tx + u] = acc[a][u];
}

__global__ __launch_bounds__(256) void k_attn(
    const float* __restrict__ x,
    const float* __restrict__ Wq, const float* __restrict__ bq,
    const float* __restrict__ Wk, const float* __restrict__ bk,
    const float* __restrict__ Wv, const float* __restrict__ bv,
    const float* __restrict__ Wp, const float* __restrict__ bp,
    const float* __restrict__ lw, const float* __restrict__ lb,
    const float* __restrict__ w3, const int* __restrict__ i3,
    float* __restrict__ out)
{
    extern __shared__ float smem[];
    float* A  = smem;            // 64*100  xw
    float* B  = A + 6400;        // 64*100  ctx
    float* Wb = B + 6400;        // 96*100  staged weight
    float* Q  = Wb + 9600;       // 64*101  q (later O)
    float* K  = Q + 6464;        // 64*101  k (later V)
    float* S  = K + 6464;        // 64*68   attn probs
    // total 39680 floats = 158720 B

    int t = threadIdx.x;
    int n = blockIdx.x;
    int ty = t >> 4, tx = t & 15;

    float wk0 = w3[n * 3 + 0], wk1 = w3[n * 3 + 1], wk2 = w3[n * 3 + 2];
    int   m0  = i3[n * 3 + 0], m1  = i3[n * 3 + 1], m2  = i3[n * 3 + 2];
    size_t self = win_off(n);
    size_t nb0 = win_off(m0), nb1 = win_off(m1), nb2 = win_off(m2);

    // ---- gather xw (A) and weighted context (B) ----
    for (int it = 0; it < 24; ++it) {
        int g   = it * 256 + t;
        int plo = g & 15;
        int gc  = g >> 4;            // 0..383
        int c   = gc % 96;
        int phi = gc / 96;           // 0..3
        int p   = phi * 16 + plo;
        int r   = p >> 3, scol = p & 7;
        size_t coff = (((size_t)c) << 16) + (size_t)(r * 256 + scol);
        A[p * 100 + c] = x[self + coff];
        B[p * 100 + c] = fmaf(wk0, x[nb0 + coff],
                         fmaf(wk1, x[nb1 + coff], wk2 * x[nb2 + coff]));
    }
    __syncthreads();

    // ---- Q = A @ Wq + bq ----
    stage_w(Wq, Wb, t);
    __syncthreads();
    gemm96(A, 100, Wb, bq, Q, 101, ty, tx);
    __syncthreads();

    // ---- K = B @ Wk + bk ----
    stage_w(Wk, Wb, t);
    __syncthreads();
    gemm96(B, 100, Wb, bk, K, 101, ty, tx);
    __syncthreads();

    // ---- S = softmax(Q K^T * scale) ----
    {
        float acc[4][4] = {};
        for (int c = 0; c < 96; ++c) {
            float qa[4], kb[4];
            #pragma unroll
            for (int a = 0; a < 4; ++a) qa[a] = Q[(4 * ty + a) * 101 + c];
            #pragma unroll
            for (int b2 = 0; b2 < 4; ++b2) kb[b2] = K[(4 * tx + b2) * 101 + c];
            #pragma unroll
            for (int a = 0; a < 4; ++a)
                #pragma unroll
                for (int b2 = 0; b2 < 4; ++b2)
                    acc[a][b2] = fmaf(qa[a], kb[b2], acc[a][b2]);
        }
        const float scale = 0.10206207261596575f;
        #pragma unroll
        for (int a = 0; a < 4; ++a)
            #pragma unroll
            for (int b2 = 0; b2 < 4; ++b2)
                S[(4 * ty + a) * 68 + 4 * tx + b2] = acc[a][b2] * scale;
    }
    __syncthreads();
    if (t < 64) {
        float m = NEG_INF;
        for (int cc = 0; cc < 64; ++cc) m = fmaxf(m, S[t * 68 + cc]);
        float sum = 0.f;
        for (int cc = 0; cc < 64; ++cc) {
            float e = __expf(S[t * 68 + cc] - m);
            S[t * 68 + cc] = e;
            sum += e;
        }
        float inv = 1.f / sum;
        for (int cc = 0; cc < 64; ++cc) S[t * 68 + cc] *= inv;
    }
    __syncthreads();

    // ---- V = B @ Wv + bv  (into K buffer; K dead) ----
    stage_w(Wv, Wb, t);
    __syncthreads();
    gemm96(B, 100, Wb, bv, K, 101, ty, tx);
    __syncthreads();
    const float* V = K;

    // ---- O = S @ V + lepe(A)  (into Q buffer; Q dead) ----
    {
        float acc[4][6];
        #pragma unroll
        for (int u = 0; u < 6; ++u) {
            int co = 6 * tx + u;
            float l0 = lb[co];
            float wr[9];
            #pragma unroll
            for (int e = 0; e < 9; ++e) wr[e] = lw[co * 9 + e];
            #pragma unroll
            for (int a = 0; a < 4; ++a) {
                int p = 4 * ty + a, r = p >> 3, sc = p & 7;
                float v = l0;
                #pragma unroll
                for (int dr = -1; dr <= 1; ++dr) {
                    int rr = r + dr;
                    if ((unsigned)rr < 8u) {
                        #pragma unroll
                        for (int dsq = -1; dsq <= 1; ++dsq) {
                            int s2 = sc + dsq;
                            if ((unsigned)s2 < 8u)
                                v = fmaf(wr[(dr + 1) * 3 + (dsq + 1)],
                                         A[(rr * 8 + s2) * 100 + co], v);
                        }
                    }
                }
                acc[a][u] = v;
            }
        }
        for (int p2 = 0; p2 < 64; ++p2) {
            float sa[4], vu[6];
            #pragma unroll
            for (int a = 0; a < 4; ++a) sa[a] = S[(4 * ty + a) * 68 + p2];
            #pragma unroll
            for (int u = 0; u < 6; ++u) vu[u] = V[p2 * 101 + 6 * tx + u];
            #pragma unroll
            for (int a = 0; a < 4; ++a)
                #pragma unroll
                for (int u = 0; u < 6; ++u)
                    acc[a][u] = fmaf(sa[a], vu[u], acc[a][u]);
        }
        #pragma unroll
        for (int a = 0; a < 4; ++a)
            #pragma unroll
            for (int u = 0; u < 6; ++u)
                Q[(4 * ty + a) * 101 + 6 * tx + u] = acc[a][u];
    }
    __syncthreads();
    const float* O = Q;

    // ---- out = O @ Wp + bp -> global ----
    stage_w(Wp, Wb, t);
    __syncthreads();
    {
        int b = n >> 10, i = (n >> 5) & 31, j = n & 31;
        float acc[4][6];
        #pragma unroll
        for (int u = 0; u < 6; ++u) {
            float bb = bp[6 * tx + u];
            #pragma unroll
            for (int a = 0; a < 4; ++a) acc[a][u] = bb;
        }
        for (int c = 0; c < 96; ++c) {
            float xa[4], wu[6];
            #pragma unroll
            for (int a = 0; a < 4; ++a) xa[a] = O[(4 * ty + a) * 101 + c];
            #pragma unroll
            for (int u = 0; u < 6; ++u) wu[u] = Wb[c * 100 + 6 * tx + u];
            #pragma unroll
            for (int a = 0; a < 4; ++a)
                #pragma unroll
                for (int u = 0; u < 6; ++u) acc[a][u] = fmaf(xa[a], wu[u], acc[a][u]);
        }
        size_t obase = (((size_t)(b * 96)) << 16) + (size_t)(i * 2048 + j * 8);
        #pragma unroll
        for (int a = 0; a < 4; ++a) {
            int p = 4 * ty + a, r = p >> 3, sc = p & 7;
            #pragma unroll
            for (int u = 0; u < 6; ++u) {
                int co = 6 * tx + u;
                out[obase + (((size_t)co) << 16) + (size_t)(r * 256 + sc)] = acc[a][u];
            }
        }
    }
}

// ---------------------------------------------------------------------------
extern "C" void kernel_launch(void* const* d_in, const int* in_sizes, int n_in,
                              void* d_out, int out_size, void* d_ws, size_t ws_size,
                              hipStream_t stream)
{
    (void)in_sizes; (void)n_in; (void)out_size; (void)ws_size;
    const float* x  = (const float*)d_in[0];
    const float* Wq = (const float*)d_in[1];
    const float* bq = (const float*)d_in[2];
    const float* Wk = (const float*)d_in[3];
    const float* bk = (const float*)d_in[4];
    const float* Wv = (const float*)d_in[5];
    const float* bv = (const float*)d_in[6];
    const float* Wp = (const float*)d_in[7];
    const float* bp = (const float*)d_in[8];
    const float* lw = (const float*)d_in[9];
    const float* lb = (const float*)d_in[10];
    float* out = (float*)d_out;

    float* ws   = (float*)d_ws;
    float* dsxT = ws;                       // 96*4096        = 393216 floats
    float* pv   = ws + 393216;              // 4096*8*3       =  98304
    int*   pi   = (int*)(ws + 491520);      // 4096*8*3       =  98304
    float* w3   = ws + 589824;              // 4096*3
    int*   i3   = (int*)(ws + 602112);      // 4096*3

    // allow >64KB dynamic LDS for the fused attention kernel (gfx950: 160 KiB/WG)
    hipFuncSetAttribute((const void*)k_attn,
                        hipFuncAttributeMaxDynamicSharedMemorySize, 158720);

    k_pool<<<1536, 256, 0, stream>>>(x, dsxT);
    k_sim<<<512, 256, 0, stream>>>(dsxT, pv, pi);
    k_topk<<<16, 256, 0, stream>>>(pv, pi, w3, i3);
    k_attn<<<4096, 256, 158720, stream>>>(x, Wq, bq, Wk, bk, Wv, bv, Wp, bp,
                                          lw, lb, w3, i3, out);
}

// Round 2
// 505.585 us; speedup vs baseline: 2.2418x; 2.2418x over previous
//
#include <hip/hip_runtime.h>

typedef __attribute__((ext_vector_type(8))) short  short8;
typedef __attribute__((ext_vector_type(4))) short  short4v;
typedef __attribute__((ext_vector_type(4))) float  f32x4;

#define NEG_INF (-3.402823466e38f)

__device__ __forceinline__ unsigned short f2bf(float f) {
    unsigned u = __builtin_bit_cast(unsigned, f);
    u += 0x7fffu + ((u >> 16) & 1u);
    return (unsigned short)(u >> 16);
}
__device__ __forceinline__ float bf2f(unsigned short h) {
    unsigned u = ((unsigned)h) << 16;
    return __builtin_bit_cast(float, u);
}

__device__ __forceinline__ void ins3(float (&tv)[3], int (&ti)[3], float v, int ci)
{
    if (v > tv[0] || (v == tv[0] && ci < ti[0])) {
        tv[2] = tv[1]; ti[2] = ti[1];
        tv[1] = tv[0]; ti[1] = ti[0];
        tv[0] = v;     ti[0] = ci;
    } else if (v > tv[1] || (v == tv[1] && ci < ti[1])) {
        tv[2] = tv[1]; ti[2] = ti[1];
        tv[1] = v;     ti[1] = ci;
    } else if (v > tv[2] || (v == tv[2] && ci < ti[2])) {
        tv[2] = v;     ti[2] = ci;
    }
}

// ------------------------- Kernel 1: maxpool (fp32, unchanged) --------------
__global__ __launch_bounds__(256) void k_pool(const float* __restrict__ x,
                                              float* __restrict__ dsxT)
{
    int gid = blockIdx.x * 256 + threadIdx.x;   // [0, 96*4096)
    int c = gid >> 12;
    int n = gid & 4095;
    int b = n >> 10, i = (n >> 5) & 31, j = n & 31;
    const float* p = x + (((size_t)(b * 96 + c)) << 16) + i * 2048 + j * 8;
    float4 m0 = *(const float4*)p;
    float4 m1 = *(const float4*)(p + 4);
    #pragma unroll
    for (int r = 1; r < 8; ++r) {
        float4 a0 = *(const float4*)(p + r * 256);
        float4 a1 = *(const float4*)(p + r * 256 + 4);
        m0.x = fmaxf(m0.x, a0.x); m0.y = fmaxf(m0.y, a0.y);
        m0.z = fmaxf(m0.z, a0.z); m0.w = fmaxf(m0.w, a0.w);
        m1.x = fmaxf(m1.x, a1.x); m1.y = fmaxf(m1.y, a1.y);
        m1.z = fmaxf(m1.z, a1.z); m1.w = fmaxf(m1.w, a1.w);
    }
    float m = fmaxf(fmaxf(fmaxf(m0.x, m0.y), fmaxf(m0.z, m0.w)),
                    fmaxf(fmaxf(m1.x, m1.y), fmaxf(m1.z, m1.w)));
    dsxT[c * 4096 + n] = m;
}

// ------------------- Kernel 2: similarity + partial top3 (fp32) -------------
__global__ __launch_bounds__(256) void k_sim(const float* __restrict__ dsxT,
                                             float* __restrict__ pv,
                                             int* __restrict__ pi)
{
    __shared__ __align__(16) float qt[96 * 64];
    __shared__ __align__(16) float ct[96 * 64];

    int t   = threadIdx.x;
    int qti = blockIdx.x >> 3;
    int ch  = blockIdx.x & 7;
    int tyq = t >> 4;
    int txc = t & 15;

    for (int f = t; f < 1536; f += 256) {
        int cr = f >> 4, nf = f & 15;
        *(float4*)&qt[cr * 64 + 4 * nf] =
            *(const float4*)&dsxT[cr * 4096 + qti * 64 + 4 * nf];
    }

    float tv[4][3]; int ti[4][3];
    #pragma unroll
    for (int a = 0; a < 4; ++a)
        #pragma unroll
        for (int k = 0; k < 3; ++k) { tv[a][k] = NEG_INF; ti[a][k] = 0x7fffffff; }

    for (int tile = 0; tile < 8; ++tile) {
        __syncthreads();
        int cbase = ch * 512 + tile * 64;
        for (int f = t; f < 1536; f += 256) {
            int cr = f >> 4, nf = f & 15;
            *(float4*)&ct[cr * 64 + 4 * nf] =
                *(const float4*)&dsxT[cr * 4096 + cbase + 4 * nf];
        }
        __syncthreads();

        float acc[4][4] = {};
        for (int kk = 0; kk < 96; ++kk) {
            float4 qv = *(float4*)&qt[kk * 64 + 4 * tyq];
            float4 cv = *(float4*)&ct[kk * 64 + 4 * txc];
            acc[0][0] = fmaf(qv.x, cv.x, acc[0][0]);
            acc[0][1] = fmaf(qv.x, cv.y, acc[0][1]);
            acc[0][2] = fmaf(qv.x, cv.z, acc[0][2]);
            acc[0][3] = fmaf(qv.x, cv.w, acc[0][3]);
            acc[1][0] = fmaf(qv.y, cv.x, acc[1][0]);
            acc[1][1] = fmaf(qv.y, cv.y, acc[1][1]);
            acc[1][2] = fmaf(qv.y, cv.z, acc[1][2]);
            acc[1][3] = fmaf(qv.y, cv.w, acc[1][3]);
            acc[2][0] = fmaf(qv.z, cv.x, acc[2][0]);
            acc[2][1] = fmaf(qv.z, cv.y, acc[2][1]);
            acc[2][2] = fmaf(qv.z, cv.z, acc[2][2]);
            acc[2][3] = fmaf(qv.z, cv.w, acc[2][3]);
            acc[3][0] = fmaf(qv.w, cv.x, acc[3][0]);
            acc[3][1] = fmaf(qv.w, cv.y, acc[3][1]);
            acc[3][2] = fmaf(qv.w, cv.z, acc[3][2]);
            acc[3][3] = fmaf(qv.w, cv.w, acc[3][3]);
        }
        #pragma unroll
        for (int b2 = 0; b2 < 4; ++b2) {
            int ci = cbase + 4 * txc + b2;
            #pragma unroll
            for (int a = 0; a < 4; ++a) ins3(tv[a], ti[a], acc[a][b2], ci);
        }
    }

    __syncthreads();
    float* svp = ct;
    int*   sip = (int*)&ct[3072];
    #pragma unroll
    for (int a = 0; a < 4; ++a) {
        int q = 4 * tyq + a;
        #pragma unroll
        for (int k = 0; k < 3; ++k) {
            svp[(q * 16 + txc) * 3 + k] = tv[a][k];
            sip[(q * 16 + txc) * 3 + k] = ti[a][k];
        }
    }
    __syncthreads();
    if (t < 64) {
        float bv[3] = {NEG_INF, NEG_INF, NEG_INF};
        int   bi[3] = {0x7fffffff, 0x7fffffff, 0x7fffffff};
        for (int e = 0; e < 48; ++e)
            ins3(bv, bi, svp[t * 48 + e], sip[t * 48 + e]);
        int n = qti * 64 + t;
        #pragma unroll
        for (int k = 0; k < 3; ++k) {
            pv[n * 24 + ch * 3 + k] = bv[k];
            pi[n * 24 + ch * 3 + k] = bi[k];
        }
    }
}

// ---------------- Kernel 2b: final top3 merge + softmax weights -------------
__global__ __launch_bounds__(256) void k_topk(const float* __restrict__ pv,
                                              const int* __restrict__ pi,
                                              float* __restrict__ w3,
                                              int* __restrict__ i3)
{
    int n = blockIdx.x * 256 + threadIdx.x;
    float bv[3] = {NEG_INF, NEG_INF, NEG_INF};
    int   bi[3] = {0x7fffffff, 0x7fffffff, 0x7fffffff};
    for (int e = 0; e < 24; ++e)
        ins3(bv, bi, pv[n * 24 + e], pi[n * 24 + e]);
    float e1 = expf(bv[1] - bv[0]);
    float e2 = expf(bv[2] - bv[0]);
    float inv = 1.f / (1.f + e1 + e2);
    w3[n * 3 + 0] = inv;
    w3[n * 3 + 1] = e1 * inv;
    w3[n * 3 + 2] = e2 * inv;
    i3[n * 3 + 0] = bi[0];
    i3[n * 3 + 1] = bi[1];
    i3[n * 3 + 2] = bi[2];
}

// -------- Kernel 0a: transpose+cast weights -> WtT[4][96(co)][96(ci)] bf16 --
__global__ __launch_bounds__(256) void k_prep(const float* __restrict__ Wq,
                                              const float* __restrict__ Wk,
                                              const float* __restrict__ Wv,
                                              const float* __restrict__ Wp,
                                              unsigned short* __restrict__ WtT)
{
    int g = blockIdx.x * 256 + threadIdx.x;      // 4*96*12 = 4608
    if (g >= 4608) return;
    int w  = g / 1152;
    int co = (g % 1152) / 12;
    int cg = g % 12;
    const float* src = (w == 0) ? Wq : (w == 1) ? Wk : (w == 2) ? Wv : Wp;
    unsigned short* dst = WtT + w * 9216 + co * 96 + 8 * cg;
    #pragma unroll
    for (int j = 0; j < 8; ++j) dst[j] = f2bf(src[(8 * cg + j) * 96 + co]);
}

// -------- Kernel 0b: x -> window-major bf16 xwg[4096][64(p)][96(c)] ---------
__global__ __launch_bounds__(768) void k_cast(const float* __restrict__ x,
                                              unsigned short* __restrict__ xwg)
{
    int n = blockIdx.x;
    int t = threadIdx.x;
    int cg = t >> 6, p = t & 63;
    int b = n >> 10, i = (n >> 5) & 31, j = n & 31;
    int h = i * 8 + (p >> 3), w = j * 8 + (p & 7);
    size_t base = (((size_t)(b * 96 + 8 * cg)) << 16) + (size_t)(h * 256 + w);
    __align__(16) unsigned short tmp[8];
    #pragma unroll
    for (int jj = 0; jj < 8; ++jj)
        tmp[jj] = f2bf(x[base + (((size_t)jj) << 16)]);
    *(short8*)&xwg[(size_t)n * 6144 + p * 96 + 8 * cg] = *(short8*)tmp;
}

// ----------------------- Kernel 3: fused MFMA window attention --------------
__device__ __forceinline__ size_t win_off(int m)
{
    return (((size_t)(m >> 10) * 96) << 16) +
           (size_t)(((m >> 5) & 31) * 2048 + (m & 31) * 8);
}

// A-operand in LDS (row-major, k-contiguous), B-operand from global WtT[96][96]
template<int NKS, int NNT>
__device__ __forceinline__ void mm_bg(const unsigned short* A_, int astr,
                                      const unsigned short* __restrict__ Wt,
                                      int mt, int l15, int quad, f32x4* acc)
{
    short8 af[NKS];
    #pragma unroll
    for (int ks = 0; ks < NKS; ++ks)
        af[ks] = *(const short8*)&A_[(mt * 16 + l15) * astr + ks * 32 + quad * 8];
    #pragma unroll
    for (int nt = 0; nt < NNT; ++nt) {
        f32x4 c = {0.f, 0.f, 0.f, 0.f};
        #pragma unroll
        for (int ks = 0; ks < NKS; ++ks) {
            short8 bf = *(const short8*)&Wt[(nt * 16 + l15) * 96 + ks * 32 + quad * 8];
            c = __builtin_amdgcn_mfma_f32_16x16x32_bf16(af[ks], bf, c, 0, 0, 0);
        }
        acc[nt] = c;
    }
}

// both operands in LDS
template<int NKS, int NNT>
__device__ __forceinline__ void mm_bl(const unsigned short* A_, int astr,
                                      const unsigned short* B_, int bstr,
                                      int mt, int l15, int quad, f32x4* acc)
{
    short8 af[NKS];
    #pragma unroll
    for (int ks = 0; ks < NKS; ++ks)
        af[ks] = *(const short8*)&A_[(mt * 16 + l15) * astr + ks * 32 + quad * 8];
    #pragma unroll
    for (int nt = 0; nt < NNT; ++nt) {
        f32x4 c = {0.f, 0.f, 0.f, 0.f};
        #pragma unroll
        for (int ks = 0; ks < NKS; ++ks) {
            short8 bf = *(const short8*)&B_[(nt * 16 + l15) * bstr + ks * 32 + quad * 8];
            c = __builtin_amdgcn_mfma_f32_16x16x32_bf16(af[ks], bf, c, 0, 0, 0);
        }
        acc[nt] = c;
    }
}

template<bool XWG>
__global__ __launch_bounds__(256) void k_attn(
    const float* __restrict__ x,
    const unsigned short* __restrict__ xwg,
    const unsigned short* __restrict__ WtT,
    const float* __restrict__ bq, const float* __restrict__ bk,
    const float* __restrict__ bv, const float* __restrict__ bp,
    const float* __restrict__ lw, const float* __restrict__ lb,
    const float* __restrict__ w3, const int* __restrict__ i3,
    float* __restrict__ out)
{
    // LDS map (bytes): As[64][104]bf16 @0, Bc[64][104] @13312, Qs[64][104] @26624,
    // Ks[64][104] @39936 | overlays: Vt[96][72] @26624, Ss[64][72] @40448,
    // Ls[64][104] @26624, Os = Bc.  Total 53248 B -> 3 blocks/CU.
    extern __shared__ __align__(16) unsigned short sm[];
    unsigned short* As = sm;            // idx 0
    unsigned short* Bc = sm + 6656;
    unsigned short* Qs = sm + 13312;
    unsigned short* Ks = sm + 19968;
    unsigned short* Vt = sm + 13312;
    unsigned short* Ss = sm + 20224;
    unsigned short* Ls = sm + 13312;
    unsigned short* Os = Bc;

    int t = threadIdx.x;
    int n = blockIdx.x;
    int lane = t & 63, mt = t >> 6;
    int l15 = lane & 15, quad = lane >> 4;

    float wk0 = w3[n * 3 + 0], wk1 = w3[n * 3 + 1], wk2 = w3[n * 3 + 2];
    int   m0  = i3[n * 3 + 0], m1 = i3[n * 3 + 1], m2 = i3[n * 3 + 2];

    // ---- P0: gather self (As) + weighted context (Bc), bf16 ----
    if (XWG) {
        #pragma unroll
        for (int it = 0; it < 3; ++it) {
            int g = it * 256 + t;            // 0..767
            int p = g / 12, cg = g % 12;
            int o = p * 96 + 8 * cg;
            short8 sv = *(const short8*)&xwg[(size_t)n * 6144 + o];
            *(short8*)&As[p * 104 + 8 * cg] = sv;
            short8 a0 = *(const short8*)&xwg[(size_t)m0 * 6144 + o];
            short8 a1 = *(const short8*)&xwg[(size_t)m1 * 6144 + o];
            short8 a2 = *(const short8*)&xwg[(size_t)m2 * 6144 + o];
            __align__(16) unsigned short rs[8];
            #pragma unroll
            for (int e = 0; e < 8; ++e) {
                float v = wk0 * bf2f((unsigned short)a0[e]) +
                          wk1 * bf2f((unsigned short)a1[e]) +
                          wk2 * bf2f((unsigned short)a2[e]);
                rs[e] = f2bf(v);
            }
            *(short8*)&Bc[p * 104 + 8 * cg] = *(short8*)rs;
        }
    } else {
        size_t so = win_off(n), o0 = win_off(m0), o1 = win_off(m1), o2 = win_off(m2);
        #pragma unroll
        for (int it = 0; it < 3; ++it) {
            int g = it * 256 + t;
            int p = g / 12, cg = g % 12;
            size_t po = (size_t)((p >> 3) * 256 + (p & 7));
            __align__(16) unsigned short ra[8], rb[8];
            #pragma unroll
            for (int jj = 0; jj < 8; ++jj) {
                size_t co = (((size_t)(8 * cg + jj)) << 16) + po;
                ra[jj] = f2bf(x[so + co]);
                rb[jj] = f2bf(wk0 * x[o0 + co] + wk1 * x[o1 + co] + wk2 * x[o2 + co]);
            }
            *(short8*)&As[p * 104 + 8 * cg] = *(short8*)ra;
            *(short8*)&Bc[p * 104 + 8 * cg] = *(short8*)rb;
        }
    }
    __syncthreads();

    // ---- P1+P2: Q = As@Wq + bq -> Qs ; K = Bc@Wk + bk -> Ks ----
    {
        f32x4 qa[6], ka[6];
        mm_bg<3, 6>(As, 104, WtT, mt, l15, quad, qa);
        mm_bg<3, 6>(Bc, 104, WtT + 9216, mt, l15, quad, ka);
        #pragma unroll
        for (int nt = 0; nt < 6; ++nt) {
            float bbq = bq[nt * 16 + l15];
            float bbk = bk[nt * 16 + l15];
            #pragma unroll
            for (int r = 0; r < 4; ++r) {
                int row = mt * 16 + quad * 4 + r;
                Qs[row * 104 + nt * 16 + l15] = f2bf(qa[nt][r] + bbq);
                Ks[row * 104 + nt * 16 + l15] = f2bf(ka[nt][r] + bbk);
            }
        }
    }
    __syncthreads();

    // ---- P3: S = softmax(Q K^T * scale) in registers ----
    float pr[4][4];   // [r][nt]
    float inv[4];
    {
        f32x4 sa[4];
        mm_bl<3, 4>(Qs, 104, Ks, 104, mt, l15, quad, sa);
        const float scale = 0.10206207261596575f;
        #pragma unroll
        for (int r = 0; r < 4; ++r) {
            float mx = fmaxf(fmaxf(sa[0][r], sa[1][r]), fmaxf(sa[2][r], sa[3][r]));
            #pragma unroll
            for (int d = 1; d < 16; d <<= 1) mx = fmaxf(mx, __shfl_xor(mx, d, 16));
            float sum = 0.f;
            #pragma unroll
            for (int nt = 0; nt < 4; ++nt) {
                float e = __expf((sa[nt][r] - mx) * scale);
                pr[r][nt] = e; sum += e;
            }
            #pragma unroll
            for (int d = 1; d < 16; d <<= 1) sum += __shfl_xor(sum, d, 16);
            inv[r] = 1.f / sum;
        }
    }
    __syncthreads();   // all Qs/Ks reads done

    // ---- P3b: write probs Ss ; P4: V = Bc@Wv + bv -> Vt (transposed) ----
    {
        #pragma unroll
        for (int r = 0; r < 4; ++r) {
            int row = mt * 16 + quad * 4 + r;
            #pragma unroll
            for (int nt = 0; nt < 4; ++nt)
                Ss[row * 72 + nt * 16 + l15] = f2bf(pr[r][nt] * inv[r]);
        }
        f32x4 va[6];
        mm_bg<3, 6>(Bc, 104, WtT + 2 * 9216, mt, l15, quad, va);
        #pragma unroll
        for (int nt = 0; nt < 6; ++nt) {
            float bbv = bv[nt * 16 + l15];
            __align__(8) unsigned short pk[4];
            #pragma unroll
            for (int r = 0; r < 4; ++r) pk[r] = f2bf(va[nt][r] + bbv);
            *(short4v*)&Vt[(nt * 16 + l15) * 72 + mt * 16 + quad * 4] = *(short4v*)pk;
        }
    }
    __syncthreads();

    // ---- P5: O = S@V -> Os (over Bc) ----
    {
        f32x4 oa[6];
        mm_bl<2, 6>(Ss, 72, Vt, 72, mt, l15, quad, oa);
        #pragma unroll
        for (int nt = 0; nt < 6; ++nt)
            #pragma unroll
            for (int r = 0; r < 4; ++r)
                Os[(mt * 16 + quad * 4 + r) * 104 + nt * 16 + l15] = f2bf(oa[nt][r]);
    }
    __syncthreads();

    // ---- P5b: lepe(As) -> Ls (over Vt/Qs) ----
    {
        int p = t & 63, cq = t >> 6;
        int c0 = 24 * cq;
        int r = p >> 3, s = p & 7;
        float res[24];
        #pragma unroll
        for (int cc = 0; cc < 24; ++cc) res[cc] = lb[c0 + cc];
        #pragma unroll
        for (int dr = -1; dr <= 1; ++dr) {
            int rr = r + dr;
            if ((unsigned)rr >= 8u) continue;
            #pragma unroll
            for (int ds_ = -1; ds_ <= 1; ++ds_) {
                int s2 = s + ds_;
                if ((unsigned)s2 >= 8u) continue;
                int pp = rr * 8 + s2;
                int e  = (dr + 1) * 3 + (ds_ + 1);
                __align__(16) unsigned short av[24];
                *(short8*)&av[0]  = *(const short8*)&As[pp * 104 + c0];
                *(short8*)&av[8]  = *(const short8*)&As[pp * 104 + c0 + 8];
                *(short8*)&av[16] = *(const short8*)&As[pp * 104 + c0 + 16];
                #pragma unroll
                for (int cc = 0; cc < 24; ++cc)
                    res[cc] = fmaf(lw[(c0 + cc) * 9 + e], bf2f(av[cc]), res[cc]);
            }
        }
        __align__(16) unsigned short lo[24];
        #pragma unroll
        for (int cc = 0; cc < 24; ++cc) lo[cc] = f2bf(res[cc]);
        *(short8*)&Ls[p * 104 + c0]      = *(short8*)&lo[0];
        *(short8*)&Ls[p * 104 + c0 + 8]  = *(short8*)&lo[8];
        *(short8*)&Ls[p * 104 + c0 + 16] = *(short8*)&lo[16];
    }
    __syncthreads();

    // ---- P6: out = (O + L) @ Wp + bp -> global ----
    {
        const unsigned short* Wp_ = WtT + 3 * 9216;
        short8 aO[3], aL[3];
        #pragma unroll
        for (int ks = 0; ks < 3; ++ks) {
            aO[ks] = *(const short8*)&Os[(mt * 16 + l15) * 104 + ks * 32 + quad * 8];
            aL[ks] = *(const short8*)&Ls[(mt * 16 + l15) * 104 + ks * 32 + quad * 8];
        }
        int b = n >> 10, i = (n >> 5) & 31, j = n & 31;
        #pragma unroll
        for (int nt = 0; nt < 6; ++nt) {
            f32x4 c = {0.f, 0.f, 0.f, 0.f};
            #pragma unroll
            for (int ks = 0; ks < 3; ++ks) {
                short8 bf = *(const short8*)&Wp_[(nt * 16 + l15) * 96 + ks * 32 + quad * 8];
                c = __builtin_amdgcn_mfma_f32_16x16x32_bf16(aO[ks], bf, c, 0, 0, 0);
                c = __builtin_amdgcn_mfma_f32_16x16x32_bf16(aL[ks], bf, c, 0, 0, 0);
            }
            int co = nt * 16 + l15;
            float bb = bp[co];
            size_t cbase = (((size_t)(b * 96 + co)) << 16) + (size_t)(i * 2048 + j * 8);
            #pragma unroll
            for (int r = 0; r < 4; ++r) {
                int p2 = mt * 16 + quad * 4 + r;
                out[cbase + (size_t)((p2 >> 3) * 256 + (p2 & 7))] = c[r] + bb;
            }
        }
    }
}

// ---------------------------------------------------------------------------
extern "C" void kernel_launch(void* const* d_in, const int* in_sizes, int n_in,
                              void* d_out, int out_size, void* d_ws, size_t ws_size,
                              hipStream_t stream)
{
    (void)in_sizes; (void)n_in; (void)out_size;
    const float* x  = (const float*)d_in[0];
    const float* Wq = (const float*)d_in[1];
    const float* bq = (const float*)d_in[2];
    const float* Wk = (const float*)d_in[3];
    const float* bk = (const float*)d_in[4];
    const float* Wv = (const float*)d_in[5];
    const float* bv = (const float*)d_in[6];
    const float* Wp = (const float*)d_in[7];
    const float* bp = (const float*)d_in[8];
    const float* lw = (const float*)d_in[9];
    const float* lb = (const float*)d_in[10];
    float* out = (float*)d_out;

    char* ws = (char*)d_ws;
    float* dsxT = (float*)ws;                               // 1,572,864 B
    float* pv   = (float*)(ws + 1572864);                   //   393,216 B
    int*   pi   = (int*)  (ws + 1966080);                   //   393,216 B
    float* w3   = (float*)(ws + 2359296);                   //    49,152 B
    int*   i3   = (int*)  (ws + 2408448);                   //    49,152 B
    unsigned short* WtT = (unsigned short*)(ws + 2457600);  //    73,728 B
    unsigned short* xwg = (unsigned short*)(ws + 2531328);  // 50,331,648 B
    bool use_xwg = (ws_size >= 52862976ull);

    hipFuncSetAttribute(reinterpret_cast<const void*>(&k_attn<true>),
                        hipFuncAttributeMaxDynamicSharedMemorySize, 53248);
    hipFuncSetAttribute(reinterpret_cast<const void*>(&k_attn<false>),
                        hipFuncAttributeMaxDynamicSharedMemorySize, 53248);

    k_prep<<<18, 256, 0, stream>>>(Wq, Wk, Wv, Wp, WtT);
    k_pool<<<1536, 256, 0, stream>>>(x, dsxT);
    k_sim<<<512, 256, 0, stream>>>(dsxT, pv, pi);
    k_topk<<<16, 256, 0, stream>>>(pv, pi, w3, i3);
    if (use_xwg) {
        k_cast<<<4096, 768, 0, stream>>>(x, xwg);
        k_attn<true><<<4096, 256, 53248, stream>>>(x, xwg, WtT, bq, bk, bv, bp,
                                                   lw, lb, w3, i3, out);
    } else {
        k_attn<false><<<4096, 256, 53248, stream>>>(x, nullptr, WtT, bq, bk, bv, bp,
                                                    lw, lb, w3, i3, out);
    }
}

// Round 4
// 448.045 us; speedup vs baseline: 2.5297x; 1.1284x over previous
//
#include <hip/hip_runtime.h>

typedef __attribute__((ext_vector_type(8))) short  short8;
typedef __attribute__((ext_vector_type(4))) float  f32x4;
typedef __attribute__((ext_vector_type(4))) unsigned int uint4v;
typedef __attribute__((ext_vector_type(2))) unsigned int uint2v;

#define NEG_INF (-3.402823466e38f)

__device__ __forceinline__ unsigned short bfbits(float f) {
    unsigned u = __builtin_bit_cast(unsigned, f);
    u += 0x7fffu + ((u >> 16) & 1u);
    return (unsigned short)(u >> 16);
}
__device__ __forceinline__ unsigned pk_bf16(float lo, float hi) {
    return (unsigned)bfbits(lo) | ((unsigned)bfbits(hi) << 16);
}
__device__ __forceinline__ float lofp(unsigned u) {
    return __builtin_bit_cast(float, u << 16);
}
__device__ __forceinline__ float hifp(unsigned u) {
    return __builtin_bit_cast(float, u & 0xffff0000u);
}

__device__ __forceinline__ void ins3(float (&tv)[3], int (&ti)[3], float v, int ci)
{
    if (v > tv[0] || (v == tv[0] && ci < ti[0])) {
        tv[2] = tv[1]; ti[2] = ti[1];
        tv[1] = tv[0]; ti[1] = ti[0];
        tv[0] = v;     ti[0] = ci;
    } else if (v > tv[1] || (v == tv[1] && ci < ti[1])) {
        tv[2] = tv[1]; ti[2] = ti[1];
        tv[1] = v;     ti[1] = ci;
    } else if (v > tv[2] || (v == tv[2] && ci < ti[2])) {
        tv[2] = v;     ti[2] = ci;
    }
}

// -------- Kernel 1 (fallback only): maxpool fp32 ----------------------------
__global__ __launch_bounds__(256) void k_pool(const float* __restrict__ x,
                                              float* __restrict__ dsxT)
{
    int gid = blockIdx.x * 256 + threadIdx.x;
    int c = gid >> 12;
    int n = gid & 4095;
    int b = n >> 10, i = (n >> 5) & 31, j = n & 31;
    const float* p = x + (((size_t)(b * 96 + c)) << 16) + i * 2048 + j * 8;
    float4 m0 = *(const float4*)p;
    float4 m1 = *(const float4*)(p + 4);
    #pragma unroll
    for (int r = 1; r < 8; ++r) {
        float4 a0 = *(const float4*)(p + r * 256);
        float4 a1 = *(const float4*)(p + r * 256 + 4);
        m0.x = fmaxf(m0.x, a0.x); m0.y = fmaxf(m0.y, a0.y);
        m0.z = fmaxf(m0.z, a0.z); m0.w = fmaxf(m0.w, a0.w);
        m1.x = fmaxf(m1.x, a1.x); m1.y = fmaxf(m1.y, a1.y);
        m1.z = fmaxf(m1.z, a1.z); m1.w = fmaxf(m1.w, a1.w);
    }
    float m = fmaxf(fmaxf(fmaxf(m0.x, m0.y), fmaxf(m0.z, m0.w)),
                    fmaxf(fmaxf(m1.x, m1.y), fmaxf(m1.z, m1.w)));
    dsxT[c * 4096 + n] = m;
}

// -------- Kernel 0b: x -> xwg bf16 [4096][64][96] + fused maxpool -----------
__global__ __launch_bounds__(768) void k_cast(const float* __restrict__ x,
                                              unsigned short* __restrict__ xwg,
                                              float* __restrict__ dsxT)
{
    int n = blockIdx.x;
    int t = threadIdx.x;
    int cg = t >> 6, p = t & 63;                 // wave == one cg (8 channels)
    int b = n >> 10, i = (n >> 5) & 31, j = n & 31;
    int h = i * 8 + (p >> 3), w = j * 8 + (p & 7);
    size_t base = (((size_t)(b * 96 + 8 * cg)) << 16) + (size_t)(h * 256 + w);
    float v[8];
    #pragma unroll
    for (int jj = 0; jj < 8; ++jj) v[jj] = x[base + (((size_t)jj) << 16)];
    uint4v pk;
    #pragma unroll
    for (int jj = 0; jj < 4; ++jj) pk[jj] = pk_bf16(v[2 * jj], v[2 * jj + 1]);
    *(uint4v*)&xwg[(size_t)n * 6144 + p * 96 + 8 * cg] = pk;
    // window max per channel via full-wave shuffle reduce
    #pragma unroll
    for (int jj = 0; jj < 8; ++jj) {
        float m = v[jj];
        #pragma unroll
        for (int d = 1; d < 64; d <<= 1) m = fmaxf(m, __shfl_xor(m, d, 64));
        if (p == 0) dsxT[(8 * cg + jj) * 4096 + n] = m;
    }
}

// -------- Kernel 2: similarity + partial top3 (fp32, 128x128 tiles) ---------
// grid 512 = 32 q-tiles(128) x 16 cand-chunks(256); block 256 (16x16).
__global__ __launch_bounds__(256) void k_sim(const float* __restrict__ dsxT,
                                             float* __restrict__ pv,
                                             int* __restrict__ pi)
{
    __shared__ __align__(16) float qt[32 * 128];   // 16384 B
    __shared__ __align__(16) float ct[32 * 144];   // 18432 B (pad 4 per 32)
    int t = threadIdx.x;
    int qti = blockIdx.x >> 4;
    int ch  = blockIdx.x & 15;
    int ty = t >> 4, tx = t & 15;
    int qb = qti * 128;

    float tv[8][3]; int ti[8][3];
    #pragma unroll
    for (int a = 0; a < 8; ++a)
        #pragma unroll
        for (int k = 0; k < 3; ++k) { tv[a][k] = NEG_INF; ti[a][k] = 0x7fffffff; }

    #pragma unroll
    for (int pass = 0; pass < 2; ++pass) {
        int cb = ch * 256 + pass * 128;
        float acc[8][8];
        #pragma unroll
        for (int a = 0; a < 8; ++a)
            #pragma unroll
            for (int e = 0; e < 8; ++e) acc[a][e] = 0.f;

        for (int kc = 0; kc < 3; ++kc) {
            __syncthreads();
            #pragma unroll
            for (int f4 = 0; f4 < 4; ++f4) {
                int f = t + f4 * 256;             // 0..1023
                int kk = f >> 5, cq = f & 31;
                *(float4*)&qt[kk * 128 + 4 * cq] =
                    *(const float4*)&dsxT[(kc * 32 + kk) * 4096 + qb + 4 * cq];
                *(float4*)&ct[kk * 144 + 4 * cq + 4 * (cq >> 3)] =
                    *(const float4*)&dsxT[(kc * 32 + kk) * 4096 + cb + 4 * cq];
            }
            __syncthreads();
            for (int kk = 0; kk < 32; ++kk) {
                float4 q0 = *(float4*)&qt[kk * 128 + 8 * ty];
                float4 q1 = *(float4*)&qt[kk * 128 + 8 * ty + 4];
                int e0 = 8 * tx, e1 = 8 * tx + 4;
                float4 c0 = *(float4*)&ct[kk * 144 + e0 + 4 * (e0 >> 5)];
                float4 c1 = *(float4*)&ct[kk * 144 + e1 + 4 * (e1 >> 5)];
                float qv[8] = {q0.x, q0.y, q0.z, q0.w, q1.x, q1.y, q1.z, q1.w};
                float cv[8] = {c0.x, c0.y, c0.z, c0.w, c1.x, c1.y, c1.z, c1.w};
                #pragma unroll
                for (int a = 0; a < 8; ++a)
                    #pragma unroll
                    for (int e = 0; e < 8; ++e)
                        acc[a][e] = fmaf(qv[a], cv[e], acc[a][e]);
            }
        }
        #pragma unroll
        for (int e = 0; e < 8; ++e) {
            int ci = cb + 8 * tx + e;
            #pragma unroll
            for (int a = 0; a < 8; ++a) ins3(tv[a], ti[a], acc[a][e], ci);
        }
    }

    // merge top3 across the 16 tx-lanes (same 8 q-rows) via butterfly shuffle
    #pragma unroll
    for (int d = 1; d < 16; d <<= 1) {
        #pragma unroll
        for (int a = 0; a < 8; ++a) {
            float ov[3]; int oi[3];
            #pragma unroll
            for (int k = 0; k < 3; ++k) {
                ov[k] = __shfl_xor(tv[a][k], d, 16);
                oi[k] = __shfl_xor(ti[a][k], d, 16);
            }
            #pragma unroll
            for (int k = 0; k < 3; ++k) ins3(tv[a], ti[a], ov[k], oi[k]);
        }
    }
    if (tx == 0) {
        #pragma unroll
        for (int a = 0; a < 8; ++a) {
            int nq = qti * 128 + 8 * ty + a;
            #pragma unroll
            for (int k = 0; k < 3; ++k) {
                pv[nq * 48 + ch * 3 + k] = tv[a][k];
                pi[nq * 48 + ch * 3 + k] = ti[a][k];
            }
        }
    }
}

// ---------------- Kernel 2b: final top3 merge + softmax weights -------------
__global__ __launch_bounds__(256) void k_topk(const float* __restrict__ pv,
                                              const int* __restrict__ pi,
                                              float* __restrict__ w3,
                                              int* __restrict__ i3)
{
    int n = blockIdx.x * 256 + threadIdx.x;
    float bv[3] = {NEG_INF, NEG_INF, NEG_INF};
    int   bi[3] = {0x7fffffff, 0x7fffffff, 0x7fffffff};
    for (int e = 0; e < 48; ++e)
        ins3(bv, bi, pv[n * 48 + e], pi[n * 48 + e]);
    float e1 = expf(bv[1] - bv[0]);
    float e2 = expf(bv[2] - bv[0]);
    float inv = 1.f / (1.f + e1 + e2);
    w3[n * 3 + 0] = inv;
    w3[n * 3 + 1] = e1 * inv;
    w3[n * 3 + 2] = e2 * inv;
    i3[n * 3 + 0] = bi[0];
    i3[n * 3 + 1] = bi[1];
    i3[n * 3 + 2] = bi[2];
}

// -------- Kernel 0a: weights -> WtT[4][96co][96ci] bf16 ; lwT[9][96] fp32 ---
__global__ __launch_bounds__(256) void k_prep(const float* __restrict__ Wq,
                                              const float* __restrict__ Wk,
                                              const float* __restrict__ Wv,
                                              const float* __restrict__ Wp,
                                              const float* __restrict__ lw,
                                              unsigned short* __restrict__ WtT,
                                              float* __restrict__ lwT)
{
    int g = blockIdx.x * 256 + threadIdx.x;
    if (g < 4608) {
        int w  = g / 1152;
        int co = (g % 1152) / 12;
        int cg = g % 12;
        const float* src = (w == 0) ? Wq : (w == 1) ? Wk : (w == 2) ? Wv : Wp;
        unsigned short* dst = WtT + w * 9216 + co * 96 + 8 * cg;
        #pragma unroll
        for (int j = 0; j < 8; ++j) dst[j] = bfbits(src[(8 * cg + j) * 96 + co]);
    } else if (g < 5472) {
        int i2 = g - 4608;
        int tap = i2 / 96, c = i2 % 96;
        lwT[tap * 96 + c] = lw[c * 9 + tap];
    }
}

// ----------------------- Kernel 3: fused MFMA window attention --------------
__device__ __forceinline__ size_t win_off(int m)
{
    return (((size_t)(m >> 10) * 96) << 16) +
           (size_t)(((m >> 5) & 31) * 2048 + (m & 31) * 8);
}

// 6 16x16 col-tiles, K=96, B-operand streamed from global WtT block
__device__ __forceinline__ void gemm_g(const short8* af,
                                       const unsigned short* __restrict__ Wt,
                                       int l15, int quad, f32x4* acc)
{
    #pragma unroll
    for (int nt = 0; nt < 6; ++nt) {
        f32x4 c = {0.f, 0.f, 0.f, 0.f};
        #pragma unroll
        for (int ks = 0; ks < 3; ++ks) {
            short8 bf = *(const short8*)&Wt[(nt * 16 + l15) * 96 + ks * 32 + quad * 8];
            c = __builtin_amdgcn_mfma_f32_16x16x32_bf16(af[ks], bf, c, 0, 0, 0);
        }
        acc[nt] = c;
    }
}

template<bool XWG>
__global__ __launch_bounds__(256, 4) void k_attn(
    const float* __restrict__ x,
    const unsigned short* __restrict__ xwg,
    const unsigned short* __restrict__ WtT,
    const float* __restrict__ lwT,
    const float* __restrict__ bq, const float* __restrict__ bk,
    const float* __restrict__ bv, const float* __restrict__ bp,
    const float* __restrict__ lb,
    const float* __restrict__ w3, const int* __restrict__ i3,
    float* __restrict__ out)
{
    // LDS: buf1[64][104] (As->Qs->Ss->Os), buf2[64][104] (Bc->Ks->Ls),
    //      Vt[96][72].  Total 40448 B -> 4 blocks/CU.
    extern __shared__ __align__(16) unsigned short sm[];
    unsigned short* buf1 = sm;            // 6656 shorts
    unsigned short* buf2 = sm + 6656;     // 6656 shorts
    unsigned short* Vt   = sm + 13312;    // 6912 shorts

    int t = threadIdx.x;
    int n = blockIdx.x;
    int lane = t & 63, mt = t >> 6;
    int l15 = lane & 15, quad = lane >> 4;

    float wk0 = w3[n * 3 + 0], wk1 = w3[n * 3 + 1], wk2 = w3[n * 3 + 2];
    int   m0  = i3[n * 3 + 0], m1 = i3[n * 3 + 1], m2 = i3[n * 3 + 2];

    // ---- P0: gather self (buf1=As) + weighted context (buf2=Bc) ----
    if (XWG) {
        #pragma unroll
        for (int it = 0; it < 3; ++it) {
            int g = it * 256 + t;
            int p = g / 12, cg = g % 12;
            int o = p * 96 + 8 * cg;
            uint4v sv = *(const uint4v*)&xwg[(size_t)n * 6144 + o];
            *(uint4v*)&buf1[p * 104 + 8 * cg] = sv;
            uint4v a0 = *(const uint4v*)&xwg[(size_t)m0 * 6144 + o];
            uint4v a1 = *(const uint4v*)&xwg[(size_t)m1 * 6144 + o];
            uint4v a2 = *(const uint4v*)&xwg[(size_t)m2 * 6144 + o];
            uint4v rs;
            #pragma unroll
            for (int e = 0; e < 4; ++e) {
                float lo = wk0 * lofp(a0[e]) + wk1 * lofp(a1[e]) + wk2 * lofp(a2[e]);
                float hi = wk0 * hifp(a0[e]) + wk1 * hifp(a1[e]) + wk2 * hifp(a2[e]);
                rs[e] = pk_bf16(lo, hi);
            }
            *(uint4v*)&buf2[p * 104 + 8 * cg] = rs;
        }
    } else {
        size_t so = win_off(n), o0 = win_off(m0), o1 = win_off(m1), o2 = win_off(m2);
        #pragma unroll
        for (int it = 0; it < 3; ++it) {
            int g = it * 256 + t;
            int p = g / 12, cg = g % 12;
            size_t po = (size_t)((p >> 3) * 256 + (p & 7));
            uint4v ra, rb;
            #pragma unroll
            for (int jj = 0; jj < 4; ++jj) {
                size_t clo = (((size_t)(8 * cg + 2 * jj)) << 16) + po;
                size_t chi = clo + ((size_t)1 << 16);
                ra[jj] = pk_bf16(x[so + clo], x[so + chi]);
                float blo = wk0 * x[o0 + clo] + wk1 * x[o1 + clo] + wk2 * x[o2 + clo];
                float bhi = wk0 * x[o0 + chi] + wk1 * x[o1 + chi] + wk2 * x[o2 + chi];
                rb[jj] = pk_bf16(blo, bhi);
            }
            *(uint4v*)&buf1[p * 104 + 8 * cg] = ra;
            *(uint4v*)&buf2[p * 104 + 8 * cg] = rb;
        }
    }
    __syncthreads();

    // ---- P1a: cache A-fragments in regs + lepe into registers ----
    short8 af_a[3], af_b[3];
    int arow = (mt * 16 + l15) * 104;
    #pragma unroll
    for (int ks = 0; ks < 3; ++ks) {
        af_a[ks] = *(const short8*)&buf1[arow + ks * 32 + quad * 8];
        af_b[ks] = *(const short8*)&buf2[arow + ks * 32 + quad * 8];
    }
    unsigned Lp[12];
    {
        int rowp = mt * 16 + l15;          // own row
        int c0 = 24 * quad;                // own 24-channel slice
        int rr0 = rowp >> 3, ss0 = rowp & 7;
        float lac[24];
        #pragma unroll
        for (int q4 = 0; q4 < 6; ++q4) {
            float4 bb = *(const float4*)&lb[c0 + 4 * q4];
            lac[4 * q4] = bb.x; lac[4 * q4 + 1] = bb.y;
            lac[4 * q4 + 2] = bb.z; lac[4 * q4 + 3] = bb.w;
        }
        #pragma unroll
        for (int dr = -1; dr <= 1; ++dr) {
            int rr = rr0 + dr;
            if ((unsigned)rr >= 8u) continue;
            #pragma unroll
            for (int dss = -1; dss <= 1; ++dss) {
                int ss = ss0 + dss;
                if ((unsigned)ss >= 8u) continue;
                int pp = rr * 8 + ss;
                int tap = (dr + 1) * 3 + (dss + 1);
                const uint4v* ap = (const uint4v*)&buf1[pp * 104 + c0];
                uint4v av0 = ap[0], av1 = ap[1], av2 = ap[2];
                float wf[24];
                #pragma unroll
                for (int q4 = 0; q4 < 6; ++q4) {
                    float4 ww = *(const float4*)&lwT[tap * 96 + c0 + 4 * q4];
                    wf[4 * q4] = ww.x; wf[4 * q4 + 1] = ww.y;
                    wf[4 * q4 + 2] = ww.z; wf[4 * q4 + 3] = ww.w;
                }
                #pragma unroll
                for (int u = 0; u < 12; ++u) {
                    unsigned uu = (u < 4) ? av0[u] : (u < 8) ? av1[u - 4] : av2[u - 8];
                    lac[2 * u]     = fmaf(wf[2 * u],     lofp(uu), lac[2 * u]);
                    lac[2 * u + 1] = fmaf(wf[2 * u + 1], hifp(uu), lac[2 * u + 1]);
                }
            }
        }
        #pragma unroll
        for (int u = 0; u < 12; ++u) Lp[u] = pk_bf16(lac[2 * u], lac[2 * u + 1]);
    }
    __syncthreads();

    // ---- P1b: Q -> buf1 (in place), K -> buf2 (in place), V -> Vt ----
    {
        f32x4 qa[6];
        gemm_g(af_a, WtT, l15, quad, qa);
        #pragma unroll
        for (int nt = 0; nt < 6; ++nt) {
            int col = nt * 16 + l15;
            float bb = bq[col];
            #pragma unroll
            for (int r = 0; r < 4; ++r)
                buf1[(mt * 16 + quad * 4 + r) * 104 + col] = bfbits(qa[nt][r] + bb);
        }
    }
    __builtin_amdgcn_sched_barrier(0);
    {
        f32x4 ka[6];
        gemm_g(af_b, WtT + 9216, l15, quad, ka);
        #pragma unroll
        for (int nt = 0; nt < 6; ++nt) {
            int col = nt * 16 + l15;
            float bb = bk[col];
            #pragma unroll
            for (int r = 0; r < 4; ++r)
                buf2[(mt * 16 + quad * 4 + r) * 104 + col] = bfbits(ka[nt][r] + bb);
        }
    }
    __builtin_amdgcn_sched_barrier(0);
    {
        f32x4 va[6];
        gemm_g(af_b, WtT + 18432, l15, quad, va);
        #pragma unroll
        for (int nt = 0; nt < 6; ++nt) {
            float bb = bv[nt * 16 + l15];
            uint2v pk;
            pk[0] = pk_bf16(va[nt][0] + bb, va[nt][1] + bb);
            pk[1] = pk_bf16(va[nt][2] + bb, va[nt][3] + bb);
            *(uint2v*)&Vt[(nt * 16 + l15) * 72 + mt * 16 + quad * 4] = pk;
        }
    }
    __syncthreads();

    // ---- P2: S = QK^T, softmax in registers ----
    float pr[4][4], inv4[4];
    {
        short8 qf[3];
        #pragma unroll
        for (int ks = 0; ks < 3; ++ks)
            qf[ks] = *(const short8*)&buf1[arow + ks * 32 + quad * 8];
        f32x4 sa[4];
        #pragma unroll
        for (int nt = 0; nt < 4; ++nt) {
            f32x4 c = {0.f, 0.f, 0.f, 0.f};
            #pragma unroll
            for (int ks = 0; ks < 3; ++ks) {
                short8 bf = *(const short8*)&buf2[(nt * 16 + l15) * 104 + ks * 32 + quad * 8];
                c = __builtin_amdgcn_mfma_f32_16x16x32_bf16(qf[ks], bf, c, 0, 0, 0);
            }
            sa[nt] = c;
        }
        const float scale = 0.10206207261596575f;
        #pragma unroll
        for (int r = 0; r < 4; ++r) {
            float mx = fmaxf(fmaxf(sa[0][r], sa[1][r]), fmaxf(sa[2][r], sa[3][r]));
            #pragma unroll
            for (int d = 1; d < 16; d <<= 1) mx = fmaxf(mx, __shfl_xor(mx, d, 16));
            float sum = 0.f;
            #pragma unroll
            for (int nt = 0; nt < 4; ++nt) {
                float e = __expf((sa[nt][r] - mx) * scale);
                pr[r][nt] = e; sum += e;
            }
            #pragma unroll
            for (int d = 1; d < 16; d <<= 1) sum += __shfl_xor(sum, d, 16);
            inv4[r] = 1.f / sum;
        }
    }
    __syncthreads();   // last barrier: protects Ss/Ls overwrite of Qs/Ks

    // ---- P3: probs -> buf1 (over Qs), lepe -> buf2 (over Ks); own rows only
    #pragma unroll
    for (int r = 0; r < 4; ++r) {
        #pragma unroll
        for (int nt = 0; nt < 4; ++nt)
            buf1[(mt * 16 + quad * 4 + r) * 104 + nt * 16 + l15] =
                bfbits(pr[r][nt] * inv4[r]);
    }
    {
        uint4v* lp = (uint4v*)&buf2[arow + 24 * quad];
        uint4v l0 = {Lp[0], Lp[1], Lp[2], Lp[3]};
        uint4v l1 = {Lp[4], Lp[5], Lp[6], Lp[7]};
        uint4v l2 = {Lp[8], Lp[9], Lp[10], Lp[11]};
        lp[0] = l0; lp[1] = l1; lp[2] = l2;
    }

    // ---- P4: O = S @ V -> buf1 (over Ss); wave-local, no barrier ----
    {
        short8 sf[2];
        sf[0] = *(const short8*)&buf1[arow + quad * 8];
        sf[1] = *(const short8*)&buf1[arow + 32 + quad * 8];
        f32x4 oa[6];
        #pragma unroll
        for (int nt = 0; nt < 6; ++nt) {
            f32x4 c = {0.f, 0.f, 0.f, 0.f};
            #pragma unroll
            for (int ks = 0; ks < 2; ++ks) {
                short8 bf = *(const short8*)&Vt[(nt * 16 + l15) * 72 + ks * 32 + quad * 8];
                c = __builtin_amdgcn_mfma_f32_16x16x32_bf16(sf[ks], bf, c, 0, 0, 0);
            }
            oa[nt] = c;
        }
        #pragma unroll
        for (int nt = 0; nt < 6; ++nt)
            #pragma unroll
            for (int r = 0; r < 4; ++r)
                buf1[(mt * 16 + quad * 4 + r) * 104 + nt * 16 + l15] = bfbits(oa[nt][r]);
    }

    // ---- P6: out = (O + L) @ Wp + bp; wave-local, no barrier ----
    {
        short8 of[3], lf[3];
        #pragma unroll
        for (int ks = 0; ks < 3; ++ks) {
            of[ks] = *(const short8*)&buf1[arow + ks * 32 + quad * 8];
            lf[ks] = *(const short8*)&buf2[arow + ks * 32 + quad * 8];
        }
        const unsigned short* Wp_ = WtT + 27648;
        int b = n >> 10, ii = (n >> 5) & 31, jj = n & 31;
        #pragma unroll
        for (int nt = 0; nt < 6; ++nt) {
            f32x4 c = {0.f, 0.f, 0.f, 0.f};
            #pragma unroll
            for (int ks = 0; ks < 3; ++ks) {
                short8 bf = *(const short8*)&Wp_[(nt * 16 + l15) * 96 + ks * 32 + quad * 8];
                c = __builtin_amdgcn_mfma_f32_16x16x32_bf16(of[ks], bf, c, 0, 0, 0);
                c = __builtin_amdgcn_mfma_f32_16x16x32_bf16(lf[ks], bf, c, 0, 0, 0);
            }
            int co = nt * 16 + l15;
            float bb = bp[co];
            size_t cbase = (((size_t)(b * 96 + co)) << 16) + (size_t)(ii * 2048 + jj * 8);
            #pragma unroll
            for (int r = 0; r < 4; ++r) {
                int p2 = mt * 16 + quad * 4 + r;
                out[cbase + (size_t)((p2 >> 3) * 256 + (p2 & 7))] = c[r] + bb;
            }
        }
    }
}

// ---------------------------------------------------------------------------
extern "C" void kernel_launch(void* const* d_in, const int* in_sizes, int n_in,
                              void* d_out, int out_size, void* d_ws, size_t ws_size,
                              hipStream_t stream)
{
    (void)in_sizes; (void)n_in; (void)out_size;
    const float* x  = (const float*)d_in[0];
    const float* Wq = (const float*)d_in[1];
    const float* bq = (const float*)d_in[2];
    const float* Wk = (const float*)d_in[3];
    const float* bk = (const float*)d_in[4];
    const float* Wv = (const float*)d_in[5];
    const float* bv = (const float*)d_in[6];
    const float* Wp = (const float*)d_in[7];
    const float* bp = (const float*)d_in[8];
    const float* lw = (const float*)d_in[9];
    const float* lb = (const float*)d_in[10];
    float* out = (float*)d_out;

    char* ws = (char*)d_ws;
    float* dsxT = (float*)ws;                               // 1,572,864 B
    float* pv   = (float*)(ws + 1572864);                   //   786,432 B
    int*   pi   = (int*)  (ws + 2359296);                   //   786,432 B
    float* w3   = (float*)(ws + 3145728);                   //    49,152 B
    int*   i3   = (int*)  (ws + 3194880);                   //    49,152 B
    unsigned short* WtT = (unsigned short*)(ws + 3244032);  //    73,728 B
    float* lwT  = (float*)(ws + 3317760);                   //     3,456 B
    unsigned short* xwg = (unsigned short*)(ws + 3321344);  // 50,331,648 B
    bool use_xwg = (ws_size >= 53652992ull);

    (void)hipFuncSetAttribute(reinterpret_cast<const void*>(&k_attn<true>),
                        hipFuncAttributeMaxDynamicSharedMemorySize, 40448);
    (void)hipFuncSetAttribute(reinterpret_cast<const void*>(&k_attn<false>),
                        hipFuncAttributeMaxDynamicSharedMemorySize, 40448);

    k_prep<<<22, 256, 0, stream>>>(Wq, Wk, Wv, Wp, lw, WtT, lwT);
    if (use_xwg) {
        k_cast<<<4096, 768, 0, stream>>>(x, xwg, dsxT);
    } else {
        k_pool<<<1536, 256, 0, stream>>>(x, dsxT);
    }
    k_sim<<<512, 256, 0, stream>>>(dsxT, pv, pi);
    k_topk<<<16, 256, 0, stream>>>(pv, pi, w3, i3);
    if (use_xwg) {
        k_attn<true><<<4096, 256, 40448, stream>>>(x, xwg, WtT, lwT, bq, bk, bv, bp,
                                                   lb, w3, i3, out);
    } else {
        k_attn<false><<<4096, 256, 40448, stream>>>(x, nullptr, WtT, lwT, bq, bk, bv, bp,
                                                    lb, w3, i3, out);
    }
}